// Round 1
// baseline (80.192 us; speedup 1.0000x reference)
//
#include <hip/hip_runtime.h>

// JitterBatch: per-sample circular roll of x[64,3,512,512] fp32.
// out[b,c,h,w] = in[b,c,(h - s2[b]) mod 512, (w - s1[b]) mod 512]
// s1 = off1[b]-32 (w shift), s2 = off2[b]-32 (h shift).
//
// Memory-bound: one float4 output per thread, aligned float4 writes.
// Source w-misalignment (s1 mod 4) handled by loading two adjacent aligned
// float4s and selecting the shifted window (wave-uniform branch).

__global__ __launch_bounds__(256) void JitterBatch_kernel(
    const float* __restrict__ in,
    const int*   __restrict__ off1,
    const int*   __restrict__ off2,
    float*       __restrict__ out,
    int n4)   // total float4 elements = 64*3*512*128
{
    const int idx = blockIdx.x * blockDim.x + threadIdx.x;
    if (idx >= n4) return;

    const int w4 = idx & 127;          // float4 index within row (128 per row)
    const int h  = (idx >> 7) & 511;   // row within image
    const int bc = idx >> 16;          // b*3 + c, in [0,192)
    const int b  = bc / 3;             // compiler: magic-multiply

    const int s1 = off1[b] - 32;       // shift along w
    const int s2 = off2[b] - 32;       // shift along h

    const int src_h = (h - s2 + 512) & 511;

    const float4* __restrict__ src_row =
        reinterpret_cast<const float4*>(in) + ((size_t)bc * 512 + src_h) * 128;

    // source float range for this output float4: [4*w4 - s1, 4*w4 - s1 + 4)
    const int t  = (w4 << 2) - s1 + 512;   // in [480, 1052], positive
    const int p0 = (t >> 2) & 127;
    const int p1 = (p0 + 1) & 127;
    const int s  = t & 3;                  // uniform within a wave (same b)

    const float4 q0 = src_row[p0];
    float4 r;
    if (s == 0) {
        r = q0;
    } else {
        const float4 q1 = src_row[p1];
        if (s == 1)      r = make_float4(q0.y, q0.z, q0.w, q1.x);
        else if (s == 2) r = make_float4(q0.z, q0.w, q1.x, q1.y);
        else             r = make_float4(q0.w, q1.x, q1.y, q1.z);
    }

    reinterpret_cast<float4*>(out)[idx] = r;
}

extern "C" void kernel_launch(void* const* d_in, const int* in_sizes, int n_in,
                              void* d_out, int out_size, void* d_ws, size_t ws_size,
                              hipStream_t stream) {
    const float* x    = (const float*)d_in[0];
    const int*   off1 = (const int*)d_in[1];
    const int*   off2 = (const int*)d_in[2];
    float*       out  = (float*)d_out;

    const int n4 = out_size / 4;                 // 12,582,912 float4s
    const int block = 256;
    const int grid  = (n4 + block - 1) / block;  // 49,152 blocks

    JitterBatch_kernel<<<grid, block, 0, stream>>>(x, off1, off2, out, n4);
}

// Round 3
// 62.205 us; speedup vs baseline: 1.2891x; 1.2891x over previous
//
#include <hip/hip_runtime.h>

// JitterBatch: per-sample circular roll of x[64,3,512,512] fp32.
// out[b,c,h,w] = in[b,c,(h - s2[b]) mod 512, (w - s1[b]) mod 512]
// s1 = off1[b]-32 (w shift), s2 = off2[b]-32 (h shift).
//
// Memory-bound. One float4 output per thread, aligned float4 writes.
// Source w-misalignment (s1 mod 4) handled by two aligned float4 loads +
// wave-uniform select. Stores are NON-TEMPORAL (native clang vector type —
// HIP's float4 class is rejected by the builtin): output is never re-read,
// so bypass L2/L3 on the write path -> the 201 MB input stays resident in
// the 256 MiB Infinity Cache across graph replays and reads become L3 hits.

typedef float fvec4 __attribute__((ext_vector_type(4)));

__global__ __launch_bounds__(256) void JitterBatch_kernel(
    const float* __restrict__ in,
    const int*   __restrict__ off1,
    const int*   __restrict__ off2,
    float*       __restrict__ out,
    int n4)   // total float4 elements = 64*3*512*128
{
    const int idx = blockIdx.x * blockDim.x + threadIdx.x;
    if (idx >= n4) return;

    const int w4 = idx & 127;          // float4 index within row (128 per row)
    const int h  = (idx >> 7) & 511;   // row within image
    const int bc = idx >> 16;          // b*3 + c, in [0,192)
    const int b  = bc / 3;             // compiler: magic-multiply

    const int s1 = off1[b] - 32;       // shift along w
    const int s2 = off2[b] - 32;       // shift along h

    const int src_h = (h - s2 + 512) & 511;

    const fvec4* __restrict__ src_row =
        reinterpret_cast<const fvec4*>(in) + ((size_t)bc * 512 + src_h) * 128;

    // source float range for this output float4: [4*w4 - s1, 4*w4 - s1 + 4)
    const int t  = (w4 << 2) - s1 + 512;   // in [480, 1052], positive
    const int p0 = (t >> 2) & 127;
    const int p1 = (p0 + 1) & 127;
    const int s  = t & 3;                  // uniform within a wave (same b)

    const fvec4 q0 = src_row[p0];
    fvec4 r;
    if (s == 0) {
        r = q0;
    } else {
        const fvec4 q1 = src_row[p1];
        if (s == 1)      r = (fvec4){q0.y, q0.z, q0.w, q1.x};
        else if (s == 2) r = (fvec4){q0.z, q0.w, q1.x, q1.y};
        else             r = (fvec4){q0.w, q1.x, q1.y, q1.z};
    }

    __builtin_nontemporal_store(r, reinterpret_cast<fvec4*>(out) + idx);
}

extern "C" void kernel_launch(void* const* d_in, const int* in_sizes, int n_in,
                              void* d_out, int out_size, void* d_ws, size_t ws_size,
                              hipStream_t stream) {
    const float* x    = (const float*)d_in[0];
    const int*   off1 = (const int*)d_in[1];
    const int*   off2 = (const int*)d_in[2];
    float*       out  = (float*)d_out;

    const int n4 = out_size / 4;                 // 12,582,912 float4s
    const int block = 256;
    const int grid  = (n4 + block - 1) / block;  // 49,152 blocks

    JitterBatch_kernel<<<grid, block, 0, stream>>>(x, off1, off2, out, n4);
}